// Round 3
// baseline (430.656 us; speedup 1.0000x reference)
//
#include <hip/hip_runtime.h>
#include <hip/hip_bf16.h>
#include <stdint.h>

#define B_ 8
#define N_ 256
#define M_ 128
#define D_ 128

typedef __attribute__((ext_vector_type(8))) short short8;
typedef __attribute__((ext_vector_type(4))) short short4v;
typedef __attribute__((ext_vector_type(4))) float f32x4;

static __device__ __forceinline__ unsigned short f2bf(float x) {
    union { float f; unsigned int u; } c; c.f = x;
    unsigned int r = (c.u + 0x7FFFu + ((c.u >> 16) & 1u)) >> 16;
    return (unsigned short)r;
}
static __device__ __forceinline__ float4 mul4(float4 a, float4 b) {
    return make_float4(a.x * b.x, a.y * b.y, a.z * b.z, a.w * b.w);
}
static __device__ __forceinline__ short8 pack8(float4 a, float4 b) {
    return (short8){(short)f2bf(a.x), (short)f2bf(a.y), (short)f2bf(a.z), (short)f2bf(a.w),
                    (short)f2bf(b.x), (short)f2bf(b.y), (short)f2bf(b.z), (short)f2bf(b.w)};
}

// ---------------- K0a: weight transposes (fp32) + bf16 casts (scaled 1/3) ----
__global__ void k0a_prep(const float* __restrict__ lin2_w, const float* __restrict__ lin3_w,
                         const float* __restrict__ mlp_w1, const float* __restrict__ mlp_w2,
                         const float* __restrict__ linv1_w, const float* __restrict__ linv2_w,
                         const float* __restrict__ linv3_w,
                         float* __restrict__ wT2, float* __restrict__ wT3,
                         float* __restrict__ wTm1, float* __restrict__ wTm2,
                         unsigned short* __restrict__ w1b, unsigned short* __restrict__ w2b,
                         unsigned short* __restrict__ w3b) {
    int gid = blockIdx.x * 256 + threadIdx.x;
    int task = gid >> 14;
    int idx = gid & 16383;
    if (task < 4) {
        int e = idx & 127, dd = idx >> 7;
        const float* src = task == 0 ? lin2_w : task == 1 ? lin3_w : task == 2 ? mlp_w1 : mlp_w2;
        float* dst = task == 0 ? wT2 : task == 1 ? wT3 : task == 2 ? wTm1 : wTm2;
        dst[dd * 128 + e] = src[e * 128 + dd];
    } else {
        const float* src = task == 4 ? linv1_w : task == 5 ? linv2_w : linv3_w;
        unsigned short* dst = task == 4 ? w1b : task == 5 ? w2b : w3b;
        dst[idx] = f2bf(src[idx] * (1.0f / 3.0f));
    }
}

// ---------------- K0b: s_v2t[b,d] = sum_m gv2[b,m,m,d] ------------------------
__global__ void k0b_trace(const float* __restrict__ gv2, float* __restrict__ s_v2t) {
    int b = blockIdx.x >> 7, d = blockIdx.x & 127;
    int lane = threadIdx.x;
    const float* p = gv2 + (size_t)b * (M_ * M_ * D_) + d;
    float acc = p[(size_t)lane * 16512] + p[(size_t)(lane + 64) * 16512];
    #pragma unroll
    for (int s = 32; s; s >>= 1) acc += __shfl_down(acc, s);
    if (lane == 0) s_v2t[b * 128 + d] = acc;
}

// ---------------- K0c: g1[b,e] = (lin1(s_v2t)+b1)*gs --------------------------
__global__ void k0c_g1(const float* __restrict__ s_v2t, const float* __restrict__ lin1_w,
                       const float* __restrict__ lin1_b, const float* __restrict__ gs,
                       float* __restrict__ g1) {
    __shared__ float sv[128];
    int b = blockIdx.x, e = threadIdx.x;
    sv[e] = s_v2t[b * 128 + e];
    __syncthreads();
    const float* w = lin1_w + e * 128;
    float acc = 0.f;
    #pragma unroll 4
    for (int dd = 0; dd < 128; ++dd) acc = fmaf(sv[dd], w[dd], acc);
    g1[b * 128 + e] = (acc + lin1_b[e]) * gs[b * 128 + e];
}

// ---------------- K1': T2 = batched per-d GEMM via bf16 MFMA ------------------
// T_d[n,c] = sum_m V_d[n,m] * G_d[m,c].  Block = (b, dc:8d, nt:64n, ch:64c),
// 8 waves, wave = one d plane.  Output: bf16 in K2-fragment layout inside the
// v_new region: chunk addr (ushorts) =
//   kb*16384 + ((cl>>4)*16 + dc)*128 + (cl&15)*8   (8 ushorts = d0..d0+7)
// where kb = (b*256+n)*2 + ch, cl = c - ch*64.  Each K2 block reads only its
// own 32 KB region before overwriting it.
__global__ __launch_bounds__(512, 4) void k1_T2(const float* __restrict__ v,
                                                const float* __restrict__ gv2,
                                                unsigned short* __restrict__ t2base) {
    __shared__ unsigned short sm[40960];   // A:[8][64][40]@0  B:[8][64][40]@20480; Lout overlays
    int bid = blockIdx.x;
    int b = bid & 7;                       // XCD-pinned per b
    int r = bid >> 3;
    int nt = r & 3, ch = (r >> 2) & 1, dc = r >> 3;
    int n0 = nt * 64, c0 = ch * 64, d0 = dc * 8;
    int t = threadIdx.x;
    int w = t >> 6, lane = t & 63, ln15 = lane & 15, kg = lane >> 4;

    f32x4 acc[4][4];
    #pragma unroll
    for (int i = 0; i < 4; ++i)
        #pragma unroll
        for (int j = 0; j < 4; ++j) acc[i][j] = (f32x4){0.f, 0.f, 0.f, 0.f};

    int d0l = (t & 1) * 4;
    int am = (t >> 1) & 31, anb = t >> 6;       // A staging coords
    int bc = (t >> 1) & 63, bmb = t >> 7;       // B staging coords

    for (int mc = 0; mc < 4; ++mc) {
        int m0 = mc * 32;
        {   // stage A: v[b, n0:n0+64, m0:m0+32, d0:d0+8] -> sm[d][n][m]
            const float* src = v + (((size_t)(b * N_ + n0) * M_ + m0 + am) * D_ + d0 + d0l);
            #pragma unroll
            for (int p = 0; p < 8; ++p) {
                int n = p * 8 + anb;
                float4 x = *(const float4*)(src + (size_t)n * (M_ * D_));
                #pragma unroll
                for (int j = 0; j < 4; ++j)
                    sm[(d0l + j) * 2560 + n * 40 + am] = f2bf(((const float*)&x)[j]);
            }
        }
        {   // stage B: gv2[b, m0:m0+32, c0:c0+64, d0:d0+8] -> sm[20480 + d][c][m]
            const float* src = gv2 + (((size_t)(b * M_ + m0) * M_ + c0 + bc) * D_ + d0 + d0l);
            #pragma unroll
            for (int p = 0; p < 8; ++p) {
                int m = p * 4 + bmb;
                float4 x = *(const float4*)(src + (size_t)m * (M_ * D_));
                #pragma unroll
                for (int j = 0; j < 4; ++j)
                    sm[20480 + (d0l + j) * 2560 + bc * 40 + m] = f2bf(((const float*)&x)[j]);
            }
        }
        __syncthreads();
        short8 af[4], bf[4];
        #pragma unroll
        for (int i = 0; i < 4; ++i)
            af[i] = *(const short8*)&sm[w * 2560 + (i * 16 + ln15) * 40 + kg * 8];
        #pragma unroll
        for (int j = 0; j < 4; ++j)
            bf[j] = *(const short8*)&sm[20480 + w * 2560 + (j * 16 + ln15) * 40 + kg * 8];
        #pragma unroll
        for (int i = 0; i < 4; ++i)
            #pragma unroll
            for (int j = 0; j < 4; ++j)
                acc[i][j] = __builtin_amdgcn_mfma_f32_16x16x32_bf16(af[i], bf[j], acc[i][j], 0, 0, 0);
        __syncthreads();
    }
    // epilogue: acc -> Lout[n][c][w] (overlays A/B), then coalesced chunk store
    #pragma unroll
    for (int i = 0; i < 4; ++i)
        #pragma unroll
        for (int j = 0; j < 4; ++j)
            #pragma unroll
            for (int q = 0; q < 4; ++q) {
                int n = i * 16 + kg * 4 + q;
                int c = j * 16 + ln15;
                sm[(n * 64 + c) * 8 + w] = f2bf(acc[i][j][q]);
            }
    __syncthreads();
    #pragma unroll
    for (int p = 0; p < 8; ++p) {
        int u = p * 512 + t;
        int n = u >> 6;
        int c = u & 63;
        short8 x = *(const short8*)&sm[(n * 64 + c) * 8];
        size_t kb = (size_t)(b * N_ + n0 + n) * 2 + ch;
        *(short8*)(t2base + kb * 16384 + (size_t)((c >> 4) * 16 + dc) * 128 + (c & 15) * 8) = x;
    }
}

// ---------------- K2'': v_new = [T2 | s*gv | gs*v] @ [W1;W2;W3]^T -------------
// Zero LDS. All A-fragments loaded fragment-direct from global; T2 is already
// in fragment layout (from K1).  Block = 64 rows (one n, c=cbase..cbase+63),
// 4 waves x 16 rows.  In-place over own T2 region (barrier after T2 reads).
__global__ __launch_bounds__(256, 4) void k2_vnew(
        const float* __restrict__ s, const float* __restrict__ v,
        const float* __restrict__ gs, const float* __restrict__ gv,
        const unsigned short* __restrict__ w1b, const unsigned short* __restrict__ w2b,
        const unsigned short* __restrict__ w3b,
        float* __restrict__ vnew) {
    int t = threadIdx.x;
    int kb = blockIdx.x;
    int rowbase = kb * 64;
    int b = kb >> 9;
    int n = (kb >> 1) & 255;
    int cbase = (kb & 1) * 64;
    int w = t >> 6, lane = t & 63, ln15 = lane & 15, kgrp = lane >> 4;
    int wr = w * 16;
    int c = cbase + wr + ln15;            // this lane's A-row's c index

    const unsigned short* t2u = (const unsigned short*)(vnew + (size_t)rowbase * 128);
    short8 a[12];
    #pragma unroll
    for (int kk = 0; kk < 4; ++kk)
        a[kk] = *(const short8*)(t2u + ((w * 4 + kk) * 4 + kgrp) * 128 + ln15 * 8);

    const float* srow = s + (size_t)(b * N_ + n) * D_;
    const float* gsr  = gs + (size_t)b * D_;
    const float* gvr  = gv + ((size_t)b * M_ + c) * D_;
    const float* vr   = v + ((size_t)(b * N_ + n) * M_ + c) * D_;
    #pragma unroll
    for (int kk = 0; kk < 4; ++kk) {
        int dd = kk * 32 + kgrp * 8;
        float4 s0 = *(const float4*)(srow + dd), s1 = *(const float4*)(srow + dd + 4);
        float4 g0 = *(const float4*)(gvr + dd),  g1 = *(const float4*)(gvr + dd + 4);
        float4 q0 = *(const float4*)(gsr + dd),  q1 = *(const float4*)(gsr + dd + 4);
        float4 v0 = *(const float4*)(vr + dd),   v1 = *(const float4*)(vr + dd + 4);
        a[4 + kk] = pack8(mul4(s0, g0), mul4(s1, g1));
        a[8 + kk] = pack8(mul4(q0, v0), mul4(q1, v1));
    }
    __syncthreads();   // T2 reads drained (vmcnt0) before in-place overwrite

    float* outp = vnew + (size_t)rowbase * 128;
    #pragma unroll
    for (int ctile = 0; ctile < 8; ++ctile) {
        f32x4 acc = {0.f, 0.f, 0.f, 0.f};
        #pragma unroll
        for (int kk = 0; kk < 12; ++kk) {
            const unsigned short* wp = (kk < 4) ? w1b : (kk < 8) ? w2b : w3b;
            short8 bv = *(const short8*)&wp[(ctile * 16 + ln15) * 128 + (kk & 3) * 32 + kgrp * 8];
            acc = __builtin_amdgcn_mfma_f32_16x16x32_bf16(a[kk], bv, acc, 0, 0, 0);
        }
        #pragma unroll
        for (int q = 0; q < 4; ++q)
            outp[(size_t)(wr + kgrp * 4 + q) * 128 + ctile * 16 + ln15] = acc[q];
    }
}

// ---------------- K3: s_vv[b,n,d] = sum_m gv[b,m,d]*v_new[b,n,m,d] ------------
__global__ void k3_svv(const float* __restrict__ gv, const float* __restrict__ vnew,
                       float* __restrict__ svv) {
    int gid = blockIdx.x * 256 + threadIdx.x;   // 65536 total
    int bn = gid >> 5, d0 = (gid & 31) * 4;
    int b = bn >> 8;
    const float* vp = vnew + (size_t)bn * 16384 + d0;
    const float* gp = gv + (size_t)b * 16384 + d0;
    float4 acc = {0.f, 0.f, 0.f, 0.f};
    #pragma unroll 4
    for (int m = 0; m < 128; ++m) {
        float4 g = *(const float4*)(gp + m * 128);
        float4 x = *(const float4*)(vp + m * 128);
        acc.x = fmaf(g.x, x.x, acc.x);
        acc.y = fmaf(g.y, x.y, acc.y);
        acc.z = fmaf(g.z, x.z, acc.z);
        acc.w = fmaf(g.w, x.w, acc.w);
    }
    *(float4*)(svv + (size_t)bn * 128 + d0) = acc;
}

// ---------------- K4: s-path linears + products + MLP -------------------------
__global__ __launch_bounds__(256) void k4_spath(
        const float* __restrict__ s, const float* __restrict__ svv,
        const float* __restrict__ g1,
        const float* __restrict__ wT2, const float* __restrict__ lin2_b,
        const float* __restrict__ wT3, const float* __restrict__ lin3_b,
        const float* __restrict__ wTm1, const float* __restrict__ mlp_b1,
        const float* __restrict__ wTm2, const float* __restrict__ mlp_b2,
        float* __restrict__ sout) {
    __shared__ float xs[8][128], xv[8][128], pre[8][128], hbuf[8][128];
    int t = threadIdx.x;
    int rowb = blockIdx.x * 8;
    int b = rowb >> 8;
    #pragma unroll
    for (int i = 0; i < 4; ++i) {
        int vi = i * 256 + t;
        int r = vi >> 7, dd = vi & 127;
        xs[r][dd] = s[(size_t)(rowb + r) * 128 + dd];
        xv[r][dd] = svv[(size_t)(rowb + r) * 128 + dd];
    }
    __syncthreads();
    int e = t & 127, h2 = t >> 7;
    float b2 = lin2_b[e], b3 = lin3_b[e], g1v = g1[b * 128 + e];
    float a2[4] = {b2, b2, b2, b2}, a3[4] = {b3, b3, b3, b3};
    for (int dd = 0; dd < 128; ++dd) {
        float w2 = wT2[dd * 128 + e], w3 = wT3[dd * 128 + e];
        #pragma unroll
        for (int r = 0; r < 4; ++r) {
            a2[r] = fmaf(xs[h2 * 4 + r][dd], w2, a2[r]);
            a3[r] = fmaf(xv[h2 * 4 + r][dd], w3, a3[r]);
        }
    }
    #pragma unroll
    for (int r = 0; r < 4; ++r) pre[h2 * 4 + r][e] = g1v * a2[r] * a3[r];
    __syncthreads();
    float bm1 = mlp_b1[e];
    float ah[4] = {bm1, bm1, bm1, bm1};
    for (int dd = 0; dd < 128; ++dd) {
        float w = wTm1[dd * 128 + e];
        #pragma unroll
        for (int r = 0; r < 4; ++r) ah[r] = fmaf(pre[h2 * 4 + r][dd], w, ah[r]);
    }
    #pragma unroll
    for (int r = 0; r < 4; ++r) hbuf[h2 * 4 + r][e] = fmaxf(ah[r], 0.f);
    __syncthreads();
    float bm2 = mlp_b2[e];
    float ao[4] = {bm2, bm2, bm2, bm2};
    for (int dd = 0; dd < 128; ++dd) {
        float w = wTm2[dd * 128 + e];
        #pragma unroll
        for (int r = 0; r < 4; ++r) ao[r] = fmaf(hbuf[h2 * 4 + r][dd], w, ao[r]);
    }
    #pragma unroll
    for (int r = 0; r < 4; ++r) sout[(size_t)(rowb + h2 * 4 + r) * 128 + e] = ao[r];
}

extern "C" void kernel_launch(void* const* d_in, const int* in_sizes, int n_in,
                              void* d_out, int out_size, void* d_ws, size_t ws_size,
                              hipStream_t stream) {
    const float* s       = (const float*)d_in[0];
    const float* v       = (const float*)d_in[1];
    const float* gs      = (const float*)d_in[2];
    const float* gv      = (const float*)d_in[3];
    const float* gv2     = (const float*)d_in[4];
    const float* lin1_w  = (const float*)d_in[5];
    const float* lin1_b  = (const float*)d_in[6];
    const float* lin2_w  = (const float*)d_in[7];
    const float* lin2_b  = (const float*)d_in[8];
    const float* lin3_w  = (const float*)d_in[9];
    const float* lin3_b  = (const float*)d_in[10];
    const float* linv1_w = (const float*)d_in[11];
    const float* linv2_w = (const float*)d_in[12];
    const float* linv3_w = (const float*)d_in[13];
    const float* mlp_w1  = (const float*)d_in[14];
    const float* mlp_b1  = (const float*)d_in[15];
    const float* mlp_w2  = (const float*)d_in[16];
    const float* mlp_b2  = (const float*)d_in[17];

    float* sout = (float*)d_out;
    float* vnew = (float*)d_out + 262144;   // v_new region; doubles as T2 (bf16,
                                            // fragment layout) between K1 and K2

    float* wsf   = (float*)d_ws;
    float* wT2   = wsf;
    float* wT3   = wsf + 16384;
    float* wTm1  = wsf + 32768;
    float* wTm2  = wsf + 49152;
    float* s_v2t = wsf + 65536;
    float* g1    = wsf + 66560;
    float* svv   = wsf + 67584;
    unsigned short* w1b = (unsigned short*)(wsf + 329728);
    unsigned short* w2b = w1b + 16384;
    unsigned short* w3b = w1b + 32768;

    k0a_prep<<<448, 256, 0, stream>>>(lin2_w, lin3_w, mlp_w1, mlp_w2,
                                      linv1_w, linv2_w, linv3_w,
                                      wT2, wT3, wTm1, wTm2, w1b, w2b, w3b);
    k0b_trace<<<1024, 64, 0, stream>>>(gv2, s_v2t);
    k0c_g1<<<8, 128, 0, stream>>>(s_v2t, lin1_w, lin1_b, gs, g1);
    k1_T2<<<1024, 512, 0, stream>>>(v, gv2, (unsigned short*)vnew);
    k2_vnew<<<4096, 256, 0, stream>>>(s, v, gs, gv, w1b, w2b, w3b, vnew);
    k3_svv<<<256, 256, 0, stream>>>(gv, vnew, svv);
    k4_spath<<<256, 256, 0, stream>>>(s, svv, g1, wT2, lin2_b, wT3, lin3_b,
                                      wTm1, mlp_b1, wTm2, mlp_b2, sout);
}

// Round 4
// 400.939 us; speedup vs baseline: 1.0741x; 1.0741x over previous
//
#include <hip/hip_runtime.h>
#include <hip/hip_bf16.h>
#include <stdint.h>

#define B_ 8
#define N_ 256
#define M_ 128
#define D_ 128

typedef __attribute__((ext_vector_type(8))) short short8;
typedef __attribute__((ext_vector_type(4))) short short4v;
typedef __attribute__((ext_vector_type(4))) float f32x4;

static __device__ __forceinline__ unsigned short f2bf(float x) {
    union { float f; unsigned int u; } c; c.f = x;
    unsigned int r = (c.u + 0x7FFFu + ((c.u >> 16) & 1u)) >> 16;
    return (unsigned short)r;
}
static __device__ __forceinline__ float4 mul4(float4 a, float4 b) {
    return make_float4(a.x * b.x, a.y * b.y, a.z * b.z, a.w * b.w);
}
static __device__ __forceinline__ short8 pack8(float4 a, float4 b) {
    return (short8){(short)f2bf(a.x), (short)f2bf(a.y), (short)f2bf(a.z), (short)f2bf(a.w),
                    (short)f2bf(b.x), (short)f2bf(b.y), (short)f2bf(b.z), (short)f2bf(b.w)};
}

// ---------------- K0a: weight transposes (fp32) + bf16 casts (scaled 1/3) ----
__global__ void k0a_prep(const float* __restrict__ lin2_w, const float* __restrict__ lin3_w,
                         const float* __restrict__ mlp_w1, const float* __restrict__ mlp_w2,
                         const float* __restrict__ linv1_w, const float* __restrict__ linv2_w,
                         const float* __restrict__ linv3_w,
                         float* __restrict__ wT2, float* __restrict__ wT3,
                         float* __restrict__ wTm1, float* __restrict__ wTm2,
                         unsigned short* __restrict__ w1b, unsigned short* __restrict__ w2b,
                         unsigned short* __restrict__ w3b) {
    int gid = blockIdx.x * 256 + threadIdx.x;
    int task = gid >> 14;
    int idx = gid & 16383;
    if (task < 4) {
        int e = idx & 127, dd = idx >> 7;
        const float* src = task == 0 ? lin2_w : task == 1 ? lin3_w : task == 2 ? mlp_w1 : mlp_w2;
        float* dst = task == 0 ? wT2 : task == 1 ? wT3 : task == 2 ? wTm1 : wTm2;
        dst[dd * 128 + e] = src[e * 128 + dd];
    } else {
        const float* src = task == 4 ? linv1_w : task == 5 ? linv2_w : linv3_w;
        unsigned short* dst = task == 4 ? w1b : task == 5 ? w2b : w3b;
        dst[idx] = f2bf(src[idx] * (1.0f / 3.0f));
    }
}

// ---------------- K0b: s_v2t[b,d] = sum_m gv2[b,m,m,d] ------------------------
__global__ void k0b_trace(const float* __restrict__ gv2, float* __restrict__ s_v2t) {
    int b = blockIdx.x >> 7, d = blockIdx.x & 127;
    int lane = threadIdx.x;
    const float* p = gv2 + (size_t)b * (M_ * M_ * D_) + d;
    float acc = p[(size_t)lane * 16512] + p[(size_t)(lane + 64) * 16512];
    #pragma unroll
    for (int s = 32; s; s >>= 1) acc += __shfl_down(acc, s);
    if (lane == 0) s_v2t[b * 128 + d] = acc;
}

// ---------------- K0c: g1[b,e] = (lin1(s_v2t)+b1)*gs --------------------------
__global__ void k0c_g1(const float* __restrict__ s_v2t, const float* __restrict__ lin1_w,
                       const float* __restrict__ lin1_b, const float* __restrict__ gs,
                       float* __restrict__ g1) {
    __shared__ float sv[128];
    int b = blockIdx.x, e = threadIdx.x;
    sv[e] = s_v2t[b * 128 + e];
    __syncthreads();
    const float* w = lin1_w + e * 128;
    float acc = 0.f;
    #pragma unroll 4
    for (int dd = 0; dd < 128; ++dd) acc = fmaf(sv[dd], w[dd], acc);
    g1[b * 128 + e] = (acc + lin1_b[e]) * gs[b * 128 + e];
}

// ---------------- K1': T2 = batched per-d GEMM via bf16 MFMA ------------------
// Output: bf16 in K2-fragment layout inside the v_new region (verified by R3).
__global__ __launch_bounds__(512, 4) void k1_T2(const float* __restrict__ v,
                                                const float* __restrict__ gv2,
                                                unsigned short* __restrict__ t2base) {
    __shared__ unsigned short sm[40960];   // A:[8][64][40]@0  B:[8][64][40]@20480; Lout overlays
    int bid = blockIdx.x;
    int b = bid & 7;                       // XCD-pinned per b
    int r = bid >> 3;
    int nt = r & 3, ch = (r >> 2) & 1, dc = r >> 3;
    int n0 = nt * 64, c0 = ch * 64, d0 = dc * 8;
    int t = threadIdx.x;
    int w = t >> 6, lane = t & 63, ln15 = lane & 15, kg = lane >> 4;

    f32x4 acc[4][4];
    #pragma unroll
    for (int i = 0; i < 4; ++i)
        #pragma unroll
        for (int j = 0; j < 4; ++j) acc[i][j] = (f32x4){0.f, 0.f, 0.f, 0.f};

    int d0l = (t & 1) * 4;
    int am = (t >> 1) & 31, anb = t >> 6;       // A staging coords
    int bc = (t >> 1) & 63, bmb = t >> 7;       // B staging coords

    for (int mc = 0; mc < 4; ++mc) {
        int m0 = mc * 32;
        {   // stage A: v[b, n0:n0+64, m0:m0+32, d0:d0+8] -> sm[d][n][m]
            const float* src = v + (((size_t)(b * N_ + n0) * M_ + m0 + am) * D_ + d0 + d0l);
            #pragma unroll
            for (int p = 0; p < 8; ++p) {
                int n = p * 8 + anb;
                float4 x = *(const float4*)(src + (size_t)n * (M_ * D_));
                #pragma unroll
                for (int j = 0; j < 4; ++j)
                    sm[(d0l + j) * 2560 + n * 40 + am] = f2bf(((const float*)&x)[j]);
            }
        }
        {   // stage B: gv2[b, m0:m0+32, c0:c0+64, d0:d0+8] -> sm[20480 + d][c][m]
            const float* src = gv2 + (((size_t)(b * M_ + m0) * M_ + c0 + bc) * D_ + d0 + d0l);
            #pragma unroll
            for (int p = 0; p < 8; ++p) {
                int m = p * 4 + bmb;
                float4 x = *(const float4*)(src + (size_t)m * (M_ * D_));
                #pragma unroll
                for (int j = 0; j < 4; ++j)
                    sm[20480 + (d0l + j) * 2560 + bc * 40 + m] = f2bf(((const float*)&x)[j]);
            }
        }
        __syncthreads();
        short8 af[4], bf[4];
        #pragma unroll
        for (int i = 0; i < 4; ++i)
            af[i] = *(const short8*)&sm[w * 2560 + (i * 16 + ln15) * 40 + kg * 8];
        #pragma unroll
        for (int j = 0; j < 4; ++j)
            bf[j] = *(const short8*)&sm[20480 + w * 2560 + (j * 16 + ln15) * 40 + kg * 8];
        #pragma unroll
        for (int i = 0; i < 4; ++i)
            #pragma unroll
            for (int j = 0; j < 4; ++j)
                acc[i][j] = __builtin_amdgcn_mfma_f32_16x16x32_bf16(af[i], bf[j], acc[i][j], 0, 0, 0);
        __syncthreads();
    }
    // epilogue: acc -> Lout[n][c][w] (overlays A/B), then coalesced chunk store
    #pragma unroll
    for (int i = 0; i < 4; ++i)
        #pragma unroll
        for (int j = 0; j < 4; ++j)
            #pragma unroll
            for (int q = 0; q < 4; ++q) {
                int n = i * 16 + kg * 4 + q;
                int c = j * 16 + ln15;
                sm[(n * 64 + c) * 8 + w] = f2bf(acc[i][j][q]);
            }
    __syncthreads();
    #pragma unroll
    for (int p = 0; p < 8; ++p) {
        int u = p * 512 + t;
        int n = u >> 6;
        int c = u & 63;
        short8 x = *(const short8*)&sm[(n * 64 + c) * 8];
        size_t kb = (size_t)(b * N_ + n0 + n) * 2 + ch;
        *(short8*)(t2base + kb * 16384 + (size_t)((c >> 4) * 16 + dc) * 128 + (c & 15) * 8) = x;
    }
}

// ---------------- K2v3: v_new = [T2 | s*gv | gs*v] @ [W1;W2;W3]^T -------------
// Weights REGISTER-RESIDENT: wave w owns e-slice w*32..+32 (2 ctiles, 24 short8
// = 96 VGPR), loaded once. Then 4 row-group iters whose 24 MFMAs have all
// operands in registers. Row-groups processed rg=3,2,1,0: T2 of rg lives in
// float-rows rg*8..rg*8+8, so only the final (rg0) stores need a barrier.
__global__ __launch_bounds__(256, 2) void k2_vnew(
        const float* __restrict__ s, const float* __restrict__ v,
        const float* __restrict__ gs, const float* __restrict__ gv,
        const unsigned short* __restrict__ w1b, const unsigned short* __restrict__ w2b,
        const unsigned short* __restrict__ w3b,
        float* __restrict__ vnew) {
    int t = threadIdx.x;
    int kb = blockIdx.x;
    int rowbase = kb * 64;
    int b = kb >> 9;
    int n = (kb >> 1) & 255;
    int cbase = (kb & 1) * 64;
    int w = t >> 6, lane = t & 63, ln15 = lane & 15, kgrp = lane >> 4;

    // weight fragments for this wave's two e-tiles (et = w*2, w*2+1)
    short8 bw0[12], bw1[12];
    #pragma unroll
    for (int kk = 0; kk < 12; ++kk) {
        const unsigned short* wp = (kk < 4) ? w1b : (kk < 8) ? w2b : w3b;
        int ko = (kk & 3) * 32 + kgrp * 8;
        bw0[kk] = *(const short8*)&wp[((w * 2) * 16 + ln15) * 128 + ko];
        bw1[kk] = *(const short8*)&wp[((w * 2 + 1) * 16 + ln15) * 128 + ko];
    }
    // s, gs broadcast slices (loop-invariant)
    const float* srow = s + (size_t)(b * N_ + n) * D_;
    const float* gsr  = gs + (size_t)b * D_;
    float4 ss[8], qq[8];
    #pragma unroll
    for (int kk = 0; kk < 4; ++kk) {
        int dd = kk * 32 + kgrp * 8;
        ss[kk * 2]     = *(const float4*)(srow + dd);
        ss[kk * 2 + 1] = *(const float4*)(srow + dd + 4);
        qq[kk * 2]     = *(const float4*)(gsr + dd);
        qq[kk * 2 + 1] = *(const float4*)(gsr + dd + 4);
    }
    const unsigned short* t2u = (const unsigned short*)(vnew + (size_t)rowbase * 128);
    float* outp = vnew + (size_t)rowbase * 128;

    #pragma unroll
    for (int it = 0; it < 4; ++it) {
        int rg = 3 - it;
        short8 aT[4];
        #pragma unroll
        for (int kk = 0; kk < 4; ++kk)
            aT[kk] = *(const short8*)(t2u + ((rg * 4 + kk) * 4 + kgrp) * 128 + ln15 * 8);
        int c = cbase + rg * 16 + ln15;
        const float* gvr = gv + ((size_t)b * M_ + c) * D_;
        const float* vr  = v + ((size_t)(b * N_ + n) * M_ + c) * D_;
        short8 aD[8];
        #pragma unroll
        for (int kk = 0; kk < 4; ++kk) {
            int dd = kk * 32 + kgrp * 8;
            float4 g0 = *(const float4*)(gvr + dd), g1 = *(const float4*)(gvr + dd + 4);
            float4 v0 = *(const float4*)(vr + dd),  v1 = *(const float4*)(vr + dd + 4);
            aD[kk]     = pack8(mul4(ss[kk * 2], g0), mul4(ss[kk * 2 + 1], g1));
            aD[4 + kk] = pack8(mul4(qq[kk * 2], v0), mul4(qq[kk * 2 + 1], v1));
        }
        f32x4 acc0 = {0.f, 0.f, 0.f, 0.f}, acc1 = {0.f, 0.f, 0.f, 0.f};
        #pragma unroll
        for (int kk = 0; kk < 12; ++kk) {
            short8 a = (kk < 4) ? aT[kk] : aD[kk - 4];
            acc0 = __builtin_amdgcn_mfma_f32_16x16x32_bf16(a, bw0[kk], acc0, 0, 0, 0);
            acc1 = __builtin_amdgcn_mfma_f32_16x16x32_bf16(a, bw1[kk], acc1, 0, 0, 0);
        }
        if (it == 3) __syncthreads();   // rg0 rows hold T2 of rg0: all waves done reading
        #pragma unroll
        for (int q = 0; q < 4; ++q) {
            int row = rg * 16 + kgrp * 4 + q;
            outp[(size_t)row * 128 + (w * 2) * 16 + ln15]     = acc0[q];
            outp[(size_t)row * 128 + (w * 2 + 1) * 16 + ln15] = acc1[q];
        }
    }
}

// ---------------- K3: s_vv[b,n,d] = sum_m gv[b,m,d]*v_new[b,n,m,d] ------------
__global__ void k3_svv(const float* __restrict__ gv, const float* __restrict__ vnew,
                       float* __restrict__ svv) {
    int gid = blockIdx.x * 256 + threadIdx.x;   // 65536 total
    int bn = gid >> 5, d0 = (gid & 31) * 4;
    int b = bn >> 8;
    const float* vp = vnew + (size_t)bn * 16384 + d0;
    const float* gp = gv + (size_t)b * 16384 + d0;
    float4 acc = {0.f, 0.f, 0.f, 0.f};
    #pragma unroll 4
    for (int m = 0; m < 128; ++m) {
        float4 g = *(const float4*)(gp + m * 128);
        float4 x = *(const float4*)(vp + m * 128);
        acc.x = fmaf(g.x, x.x, acc.x);
        acc.y = fmaf(g.y, x.y, acc.y);
        acc.z = fmaf(g.z, x.z, acc.z);
        acc.w = fmaf(g.w, x.w, acc.w);
    }
    *(float4*)(svv + (size_t)bn * 128 + d0) = acc;
}

// ---------------- K4: s-path linears + products + MLP -------------------------
__global__ __launch_bounds__(256) void k4_spath(
        const float* __restrict__ s, const float* __restrict__ svv,
        const float* __restrict__ g1,
        const float* __restrict__ wT2, const float* __restrict__ lin2_b,
        const float* __restrict__ wT3, const float* __restrict__ lin3_b,
        const float* __restrict__ wTm1, const float* __restrict__ mlp_b1,
        const float* __restrict__ wTm2, const float* __restrict__ mlp_b2,
        float* __restrict__ sout) {
    __shared__ float xs[8][128], xv[8][128], pre[8][128], hbuf[8][128];
    int t = threadIdx.x;
    int rowb = blockIdx.x * 8;
    int b = rowb >> 8;
    #pragma unroll
    for (int i = 0; i < 4; ++i) {
        int vi = i * 256 + t;
        int r = vi >> 7, dd = vi & 127;
        xs[r][dd] = s[(size_t)(rowb + r) * 128 + dd];
        xv[r][dd] = svv[(size_t)(rowb + r) * 128 + dd];
    }
    __syncthreads();
    int e = t & 127, h2 = t >> 7;
    float b2 = lin2_b[e], b3 = lin3_b[e], g1v = g1[b * 128 + e];
    float a2[4] = {b2, b2, b2, b2}, a3[4] = {b3, b3, b3, b3};
    for (int dd = 0; dd < 128; ++dd) {
        float w2 = wT2[dd * 128 + e], w3 = wT3[dd * 128 + e];
        #pragma unroll
        for (int r = 0; r < 4; ++r) {
            a2[r] = fmaf(xs[h2 * 4 + r][dd], w2, a2[r]);
            a3[r] = fmaf(xv[h2 * 4 + r][dd], w3, a3[r]);
        }
    }
    #pragma unroll
    for (int r = 0; r < 4; ++r) pre[h2 * 4 + r][e] = g1v * a2[r] * a3[r];
    __syncthreads();
    float bm1 = mlp_b1[e];
    float ah[4] = {bm1, bm1, bm1, bm1};
    for (int dd = 0; dd < 128; ++dd) {
        float w = wTm1[dd * 128 + e];
        #pragma unroll
        for (int r = 0; r < 4; ++r) ah[r] = fmaf(pre[h2 * 4 + r][dd], w, ah[r]);
    }
    #pragma unroll
    for (int r = 0; r < 4; ++r) hbuf[h2 * 4 + r][e] = fmaxf(ah[r], 0.f);
    __syncthreads();
    float bm2 = mlp_b2[e];
    float ao[4] = {bm2, bm2, bm2, bm2};
    for (int dd = 0; dd < 128; ++dd) {
        float w = wTm2[dd * 128 + e];
        #pragma unroll
        for (int r = 0; r < 4; ++r) ao[r] = fmaf(hbuf[h2 * 4 + r][dd], w, ao[r]);
    }
    #pragma unroll
    for (int r = 0; r < 4; ++r) sout[(size_t)(rowb + h2 * 4 + r) * 128 + e] = ao[r];
}

extern "C" void kernel_launch(void* const* d_in, const int* in_sizes, int n_in,
                              void* d_out, int out_size, void* d_ws, size_t ws_size,
                              hipStream_t stream) {
    const float* s       = (const float*)d_in[0];
    const float* v       = (const float*)d_in[1];
    const float* gs      = (const float*)d_in[2];
    const float* gv      = (const float*)d_in[3];
    const float* gv2     = (const float*)d_in[4];
    const float* lin1_w  = (const float*)d_in[5];
    const float* lin1_b  = (const float*)d_in[6];
    const float* lin2_w  = (const float*)d_in[7];
    const float* lin2_b  = (const float*)d_in[8];
    const float* lin3_w  = (const float*)d_in[9];
    const float* lin3_b  = (const float*)d_in[10];
    const float* linv1_w = (const float*)d_in[11];
    const float* linv2_w = (const float*)d_in[12];
    const float* linv3_w = (const float*)d_in[13];
    const float* mlp_w1  = (const float*)d_in[14];
    const float* mlp_b1  = (const float*)d_in[15];
    const float* mlp_w2  = (const float*)d_in[16];
    const float* mlp_b2  = (const float*)d_in[17];

    float* sout = (float*)d_out;
    float* vnew = (float*)d_out + 262144;   // v_new region; doubles as T2 (bf16,
                                            // fragment layout) between K1 and K2

    float* wsf   = (float*)d_ws;
    float* wT2   = wsf;
    float* wT3   = wsf + 16384;
    float* wTm1  = wsf + 32768;
    float* wTm2  = wsf + 49152;
    float* s_v2t = wsf + 65536;
    float* g1    = wsf + 66560;
    float* svv   = wsf + 67584;
    unsigned short* w1b = (unsigned short*)(wsf + 329728);
    unsigned short* w2b = w1b + 16384;
    unsigned short* w3b = w1b + 32768;

    k0a_prep<<<448, 256, 0, stream>>>(lin2_w, lin3_w, mlp_w1, mlp_w2,
                                      linv1_w, linv2_w, linv3_w,
                                      wT2, wT3, wTm1, wTm2, w1b, w2b, w3b);
    k0b_trace<<<1024, 64, 0, stream>>>(gv2, s_v2t);
    k0c_g1<<<8, 128, 0, stream>>>(s_v2t, lin1_w, lin1_b, gs, g1);
    k1_T2<<<1024, 512, 0, stream>>>(v, gv2, (unsigned short*)vnew);
    k2_vnew<<<4096, 256, 0, stream>>>(s, v, gs, gv, w1b, w2b, w3b, vnew);
    k3_svv<<<256, 256, 0, stream>>>(gv, vnew, svv);
    k4_spath<<<256, 256, 0, stream>>>(s, svv, g1, wT2, lin2_b, wT3, lin3_b,
                                      wTm1, mlp_b1, wTm2, mlp_b2, sout);
}

// Round 5
// 276.913 us; speedup vs baseline: 1.5552x; 1.4479x over previous
//
#include <hip/hip_runtime.h>
#include <hip/hip_bf16.h>
#include <stdint.h>

#define B_ 8
#define N_ 256
#define M_ 128
#define D_ 128

typedef __attribute__((ext_vector_type(8))) short short8;
typedef __attribute__((ext_vector_type(4))) short short4v;
typedef __attribute__((ext_vector_type(4))) float f32x4;

static __device__ __forceinline__ unsigned short f2bf(float x) {
    union { float f; unsigned int u; } c; c.f = x;
    unsigned int r = (c.u + 0x7FFFu + ((c.u >> 16) & 1u)) >> 16;
    return (unsigned short)r;
}
static __device__ __forceinline__ float4 mul4(float4 a, float4 b) {
    return make_float4(a.x * b.x, a.y * b.y, a.z * b.z, a.w * b.w);
}
static __device__ __forceinline__ short8 pack8(float4 a, float4 b) {
    return (short8){(short)f2bf(a.x), (short)f2bf(a.y), (short)f2bf(a.z), (short)f2bf(a.w),
                    (short)f2bf(b.x), (short)f2bf(b.y), (short)f2bf(b.z), (short)f2bf(b.w)};
}

// ---------------- K0a: weight transposes (fp32) + wfrag (bf16, frag order) ---
// wfrag[et][kk][kgrp][ln15][j] = W_mat[et*16+ln15][(kk&3)*32+kgrp*8+j] / 3
// (mat = kk/4: 0->linv1(T part), 1->linv2(s*gv), 2->linv3(gs*v)); 96 KB total.
__global__ void k0a_prep(const float* __restrict__ lin2_w, const float* __restrict__ lin3_w,
                         const float* __restrict__ mlp_w1, const float* __restrict__ mlp_w2,
                         const float* __restrict__ linv1_w, const float* __restrict__ linv2_w,
                         const float* __restrict__ linv3_w,
                         float* __restrict__ wT2, float* __restrict__ wT3,
                         float* __restrict__ wTm1, float* __restrict__ wTm2,
                         unsigned short* __restrict__ wfrag) {
    int gid = blockIdx.x * 256 + threadIdx.x;
    int task = gid >> 14;
    int idx = gid & 16383;
    if (task < 4) {
        int e = idx & 127, dd = idx >> 7;
        const float* src = task == 0 ? lin2_w : task == 1 ? lin3_w : task == 2 ? mlp_w1 : mlp_w2;
        float* dst = task == 0 ? wT2 : task == 1 ? wT3 : task == 2 ? wTm1 : wTm2;
        dst[dd * 128 + e] = src[e * 128 + dd];
    } else {
        int mat = task - 4;
        const float* src = mat == 0 ? linv1_w : mat == 1 ? linv2_w : linv3_w;
        int e = idx >> 7, k = idx & 127;
        int dst = ((((e >> 4) * 12 + (mat * 4 + (k >> 5))) * 4 + ((k >> 3) & 3)) * 16 + (e & 15)) * 8
                  + (k & 7);
        wfrag[dst] = f2bf(src[idx] * (1.0f / 3.0f));
    }
}

// ---------------- K0b: s_v2t[b,d] = sum_m gv2[b,m,m,d] ------------------------
__global__ void k0b_trace(const float* __restrict__ gv2, float* __restrict__ s_v2t) {
    int b = blockIdx.x >> 7, d = blockIdx.x & 127;
    int lane = threadIdx.x;
    const float* p = gv2 + (size_t)b * (M_ * M_ * D_) + d;
    float acc = p[(size_t)lane * 16512] + p[(size_t)(lane + 64) * 16512];
    #pragma unroll
    for (int s = 32; s; s >>= 1) acc += __shfl_down(acc, s);
    if (lane == 0) s_v2t[b * 128 + d] = acc;
}

// ---------------- K0c: g1[b,e] = (lin1(s_v2t)+b1)*gs --------------------------
__global__ void k0c_g1(const float* __restrict__ s_v2t, const float* __restrict__ lin1_w,
                       const float* __restrict__ lin1_b, const float* __restrict__ gs,
                       float* __restrict__ g1) {
    __shared__ float sv[128];
    int b = blockIdx.x, e = threadIdx.x;
    sv[e] = s_v2t[b * 128 + e];
    __syncthreads();
    const float* w = lin1_w + e * 128;
    float acc = 0.f;
    #pragma unroll 4
    for (int dd = 0; dd < 128; ++dd) acc = fmaf(sv[dd], w[dd], acc);
    g1[b * 128 + e] = (acc + lin1_b[e]) * gs[b * 128 + e];
}

// ---------------- K1': T2 = batched per-d GEMM via bf16 MFMA ------------------
// Output: bf16 in K2-fragment layout inside the v_new region (verified R3/R4).
__global__ __launch_bounds__(512, 4) void k1_T2(const float* __restrict__ v,
                                                const float* __restrict__ gv2,
                                                unsigned short* __restrict__ t2base) {
    __shared__ unsigned short sm[40960];   // A:[8][64][40]@0  B:[8][64][40]@20480; Lout overlays
    int bid = blockIdx.x;
    int b = bid & 7;                       // XCD-pinned per b
    int r = bid >> 3;
    int nt = r & 3, ch = (r >> 2) & 1, dc = r >> 3;
    int n0 = nt * 64, c0 = ch * 64, d0 = dc * 8;
    int t = threadIdx.x;
    int w = t >> 6, lane = t & 63, ln15 = lane & 15, kg = lane >> 4;

    f32x4 acc[4][4];
    #pragma unroll
    for (int i = 0; i < 4; ++i)
        #pragma unroll
        for (int j = 0; j < 4; ++j) acc[i][j] = (f32x4){0.f, 0.f, 0.f, 0.f};

    int d0l = (t & 1) * 4;
    int am = (t >> 1) & 31, anb = t >> 6;       // A staging coords
    int bc = (t >> 1) & 63, bmb = t >> 7;       // B staging coords

    for (int mc = 0; mc < 4; ++mc) {
        int m0 = mc * 32;
        {   // stage A: v[b, n0:n0+64, m0:m0+32, d0:d0+8] -> sm[d][n][m]
            const float* src = v + (((size_t)(b * N_ + n0) * M_ + m0 + am) * D_ + d0 + d0l);
            #pragma unroll
            for (int p = 0; p < 8; ++p) {
                int n = p * 8 + anb;
                float4 x = *(const float4*)(src + (size_t)n * (M_ * D_));
                #pragma unroll
                for (int j = 0; j < 4; ++j)
                    sm[(d0l + j) * 2560 + n * 40 + am] = f2bf(((const float*)&x)[j]);
            }
        }
        {   // stage B: gv2[b, m0:m0+32, c0:c0+64, d0:d0+8] -> sm[20480 + d][c][m]
            const float* src = gv2 + (((size_t)(b * M_ + m0) * M_ + c0 + bc) * D_ + d0 + d0l);
            #pragma unroll
            for (int p = 0; p < 8; ++p) {
                int m = p * 4 + bmb;
                float4 x = *(const float4*)(src + (size_t)m * (M_ * D_));
                #pragma unroll
                for (int j = 0; j < 4; ++j)
                    sm[20480 + (d0l + j) * 2560 + bc * 40 + m] = f2bf(((const float*)&x)[j]);
            }
        }
        __syncthreads();
        short8 af[4], bf[4];
        #pragma unroll
        for (int i = 0; i < 4; ++i)
            af[i] = *(const short8*)&sm[w * 2560 + (i * 16 + ln15) * 40 + kg * 8];
        #pragma unroll
        for (int j = 0; j < 4; ++j)
            bf[j] = *(const short8*)&sm[20480 + w * 2560 + (j * 16 + ln15) * 40 + kg * 8];
        #pragma unroll
        for (int i = 0; i < 4; ++i)
            #pragma unroll
            for (int j = 0; j < 4; ++j)
                acc[i][j] = __builtin_amdgcn_mfma_f32_16x16x32_bf16(af[i], bf[j], acc[i][j], 0, 0, 0);
        __syncthreads();
    }
    // epilogue: acc -> Lout[n][c][w] (overlays A/B), then coalesced chunk store
    #pragma unroll
    for (int i = 0; i < 4; ++i)
        #pragma unroll
        for (int j = 0; j < 4; ++j)
            #pragma unroll
            for (int q = 0; q < 4; ++q) {
                int n = i * 16 + kg * 4 + q;
                int c = j * 16 + ln15;
                sm[(n * 64 + c) * 8 + w] = f2bf(acc[i][j][q]);
            }
    __syncthreads();
    #pragma unroll
    for (int p = 0; p < 8; ++p) {
        int u = p * 512 + t;
        int n = u >> 6;
        int c = u & 63;
        short8 x = *(const short8*)&sm[(n * 64 + c) * 8];
        size_t kb = (size_t)(b * N_ + n0 + n) * 2 + ch;
        *(short8*)(t2base + kb * 16384 + (size_t)((c >> 4) * 16 + dc) * 128 + (c & 15) * 8) = x;
    }
}

// ---------------- K2v5: v_new GEMM, weights in LDS; fused s_vv ----------------
// Block = one (b,n) = 128 rows x 128 e.  Weights (96 KB, fragment-ordered)
// staged to LDS once; B-fragments via conflict-free ds_read_b128.  Wave w owns
// row-tiles rt=2w,2w+1 (rt = ch*4+rg).  T2 read up front + one barrier ->
// in-place overwrite safe.  s_vv[b,n,e] = sum_c gv[b,c,e]*vnew fused:
// in-register psum + kgrp shuffle + 2KB LDS cross-wave reduce (kernel k3 gone).
__global__ __launch_bounds__(256, 1) void k2_vnew(
        const float* __restrict__ s, const float* __restrict__ v,
        const float* __restrict__ gs, const float* __restrict__ gv,
        const unsigned short* __restrict__ wfrag,
        float* __restrict__ vnew, float* __restrict__ svv) {
    __shared__ unsigned short smw[49152];
    __shared__ float part[4][128];
    int t = threadIdx.x;
    int kb2 = blockIdx.x;              // = b*256 + n
    int b = kb2 >> 8;
    int w = t >> 6, lane = t & 63, ln15 = lane & 15, kgrp = lane >> 4;

    // stage weights -> LDS (vectorized copy; overlaps T2/s/gs loads below)
    #pragma unroll
    for (int r = 0; r < 24; ++r) {
        int idx = (r * 256 + t) * 8;
        *(short8*)&smw[idx] = *(const short8*)(wfrag + idx);
    }
    // T2 fragments for BOTH row-tiles up front (in-place hazard)
    const unsigned short* t2u = (const unsigned short*)(vnew + (size_t)kb2 * 16384);
    short8 aT[2][4];
    #pragma unroll
    for (int h = 0; h < 2; ++h) {
        int rt = w * 2 + h;
        const unsigned short* tb = t2u + (rt >> 2) * 16384 + ((rt & 3) * 16 + kgrp) * 128 + ln15 * 8;
        #pragma unroll
        for (int kk = 0; kk < 4; ++kk)
            aT[h][kk] = *(const short8*)(tb + kk * 512);
    }
    // s, gs slices (loop-invariant)
    const float* srow = s + (size_t)kb2 * 128;
    const float* gsr  = gs + (size_t)b * 128;
    float4 ss[8], qq[8];
    #pragma unroll
    for (int kk = 0; kk < 4; ++kk) {
        int dd = kk * 32 + kgrp * 8;
        ss[kk * 2]     = *(const float4*)(srow + dd);
        ss[kk * 2 + 1] = *(const float4*)(srow + dd + 4);
        qq[kk * 2]     = *(const float4*)(gsr + dd);
        qq[kk * 2 + 1] = *(const float4*)(gsr + dd + 4);
    }
    __syncthreads();   // weights in LDS; all T2 reads drained before any store

    float psum[8] = {0.f, 0.f, 0.f, 0.f, 0.f, 0.f, 0.f, 0.f};
    #pragma unroll
    for (int h = 0; h < 2; ++h) {
        int rt = w * 2 + h;
        int ca = rt * 16 + ln15;                     // A-row c (derived parts)
        const float* gvr = gv + ((size_t)b * M_ + ca) * D_;
        const float* vr  = v + ((size_t)kb2 * M_ + ca) * D_;
        short8 aD[8];
        #pragma unroll
        for (int kk = 0; kk < 4; ++kk) {
            int dd = kk * 32 + kgrp * 8;
            float4 g0 = *(const float4*)(gvr + dd), g1 = *(const float4*)(gvr + dd + 4);
            float4 v0 = *(const float4*)(vr + dd),  v1 = *(const float4*)(vr + dd + 4);
            aD[kk]     = pack8(mul4(ss[kk * 2], g0), mul4(ss[kk * 2 + 1], g1));
            aD[4 + kk] = pack8(mul4(qq[kk * 2], v0), mul4(qq[kk * 2 + 1], v1));
        }
        float* outp = vnew + (size_t)kb2 * 16384 + (rt >> 2) * 8192;
        int rowl = (rt & 3) * 16 + kgrp * 4;         // output c row base (local)
        const float* grow = gv + ((size_t)b * M_ + rt * 16 + kgrp * 4) * D_;
        #pragma unroll
        for (int ct = 0; ct < 8; ++ct) {
            f32x4 acc = {0.f, 0.f, 0.f, 0.f};
            #pragma unroll
            for (int kk = 0; kk < 12; ++kk) {
                short8 a = (kk < 4) ? aT[h][kk] : aD[kk - 4];
                short8 bf = *(const short8*)&smw[(((ct * 12 + kk) * 4 + kgrp) * 16 + ln15) * 8];
                acc = __builtin_amdgcn_mfma_f32_16x16x32_bf16(a, bf, acc, 0, 0, 0);
            }
            int e = ct * 16 + ln15;
            #pragma unroll
            for (int q = 0; q < 4; ++q) {
                outp[(size_t)(rowl + q) * 128 + e] = acc[q];
                psum[ct] = fmaf(grow[(size_t)q * 128 + e], acc[q], psum[ct]);
            }
        }
    }
    // reduce psum over kgrp (lanes xor 16,32), then across waves via LDS
    #pragma unroll
    for (int ct = 0; ct < 8; ++ct) {
        psum[ct] += __shfl_xor(psum[ct], 16);
        psum[ct] += __shfl_xor(psum[ct], 32);
    }
    if (kgrp == 0) {
        #pragma unroll
        for (int ct = 0; ct < 8; ++ct) part[w][ct * 16 + ln15] = psum[ct];
    }
    __syncthreads();
    if (t < 128) svv[(size_t)kb2 * 128 + t] = part[0][t] + part[1][t] + part[2][t] + part[3][t];
}

// ---------------- K4: s-path linears + products + MLP -------------------------
__global__ __launch_bounds__(256) void k4_spath(
        const float* __restrict__ s, const float* __restrict__ svv,
        const float* __restrict__ g1,
        const float* __restrict__ wT2, const float* __restrict__ lin2_b,
        const float* __restrict__ wT3, const float* __restrict__ lin3_b,
        const float* __restrict__ wTm1, const float* __restrict__ mlp_b1,
        const float* __restrict__ wTm2, const float* __restrict__ mlp_b2,
        float* __restrict__ sout) {
    __shared__ float xs[8][128], xv[8][128], pre[8][128], hbuf[8][128];
    int t = threadIdx.x;
    int rowb = blockIdx.x * 8;
    int b = rowb >> 8;
    #pragma unroll
    for (int i = 0; i < 4; ++i) {
        int vi = i * 256 + t;
        int r = vi >> 7, dd = vi & 127;
        xs[r][dd] = s[(size_t)(rowb + r) * 128 + dd];
        xv[r][dd] = svv[(size_t)(rowb + r) * 128 + dd];
    }
    __syncthreads();
    int e = t & 127, h2 = t >> 7;
    float b2 = lin2_b[e], b3 = lin3_b[e], g1v = g1[b * 128 + e];
    float a2[4] = {b2, b2, b2, b2}, a3[4] = {b3, b3, b3, b3};
    for (int dd = 0; dd < 128; ++dd) {
        float w2 = wT2[dd * 128 + e], w3 = wT3[dd * 128 + e];
        #pragma unroll
        for (int r = 0; r < 4; ++r) {
            a2[r] = fmaf(xs[h2 * 4 + r][dd], w2, a2[r]);
            a3[r] = fmaf(xv[h2 * 4 + r][dd], w3, a3[r]);
        }
    }
    #pragma unroll
    for (int r = 0; r < 4; ++r) pre[h2 * 4 + r][e] = g1v * a2[r] * a3[r];
    __syncthreads();
    float bm1 = mlp_b1[e];
    float ah[4] = {bm1, bm1, bm1, bm1};
    for (int dd = 0; dd < 128; ++dd) {
        float w = wTm1[dd * 128 + e];
        #pragma unroll
        for (int r = 0; r < 4; ++r) ah[r] = fmaf(pre[h2 * 4 + r][dd], w, ah[r]);
    }
    #pragma unroll
    for (int r = 0; r < 4; ++r) hbuf[h2 * 4 + r][e] = fmaxf(ah[r], 0.f);
    __syncthreads();
    float bm2 = mlp_b2[e];
    float ao[4] = {bm2, bm2, bm2, bm2};
    for (int dd = 0; dd < 128; ++dd) {
        float w = wTm2[dd * 128 + e];
        #pragma unroll
        for (int r = 0; r < 4; ++r) ao[r] = fmaf(hbuf[h2 * 4 + r][dd], w, ao[r]);
    }
    #pragma unroll
    for (int r = 0; r < 4; ++r) sout[(size_t)(rowb + h2 * 4 + r) * 128 + e] = ao[r];
}

extern "C" void kernel_launch(void* const* d_in, const int* in_sizes, int n_in,
                              void* d_out, int out_size, void* d_ws, size_t ws_size,
                              hipStream_t stream) {
    const float* s       = (const float*)d_in[0];
    const float* v       = (const float*)d_in[1];
    const float* gs      = (const float*)d_in[2];
    const float* gv      = (const float*)d_in[3];
    const float* gv2     = (const float*)d_in[4];
    const float* lin1_w  = (const float*)d_in[5];
    const float* lin1_b  = (const float*)d_in[6];
    const float* lin2_w  = (const float*)d_in[7];
    const float* lin2_b  = (const float*)d_in[8];
    const float* lin3_w  = (const float*)d_in[9];
    const float* lin3_b  = (const float*)d_in[10];
    const float* linv1_w = (const float*)d_in[11];
    const float* linv2_w = (const float*)d_in[12];
    const float* linv3_w = (const float*)d_in[13];
    const float* mlp_w1  = (const float*)d_in[14];
    const float* mlp_b1  = (const float*)d_in[15];
    const float* mlp_w2  = (const float*)d_in[16];
    const float* mlp_b2  = (const float*)d_in[17];

    float* sout = (float*)d_out;
    float* vnew = (float*)d_out + 262144;   // v_new region; doubles as T2 (bf16,
                                            // fragment layout) between K1 and K2

    float* wsf   = (float*)d_ws;
    float* wT2   = wsf;
    float* wT3   = wsf + 16384;
    float* wTm1  = wsf + 32768;
    float* wTm2  = wsf + 49152;
    float* s_v2t = wsf + 65536;
    float* g1    = wsf + 66560;
    float* svv   = wsf + 67584;
    unsigned short* wfrag = (unsigned short*)(wsf + 329728);   // 96 KB

    k0a_prep<<<448, 256, 0, stream>>>(lin2_w, lin3_w, mlp_w1, mlp_w2,
                                      linv1_w, linv2_w, linv3_w,
                                      wT2, wT3, wTm1, wTm2, wfrag);
    k0b_trace<<<1024, 64, 0, stream>>>(gv2, s_v2t);
    k0c_g1<<<8, 128, 0, stream>>>(s_v2t, lin1_w, lin1_b, gs, g1);
    k1_T2<<<1024, 512, 0, stream>>>(v, gv2, (unsigned short*)vnew);
    k2_vnew<<<2048, 256, 0, stream>>>(s, v, gs, gv, wfrag, vnew, svv);
    k4_spath<<<256, 256, 0, stream>>>(s, svv, g1, wT2, lin2_b, wT3, lin3_b,
                                      wTm1, mlp_b1, wTm2, mlp_b2, sout);
}